// Round 7
// baseline (668.724 us; speedup 1.0000x reference)
//
#include <hip/hip_runtime.h>

// Reference: x[65536][1024] f32, weight[128][1024] f32 -> out[128][1024] f32.
// out[i,j] = exp(s_i*t_j)/det_i; s=rowsum(w), t=colsum(w), c=colsum(x),
// det_i = sum_k exp(s_i*c_k).  Mandatory traffic: 256 MiB cold read of x.
//
// ROUND 7 = COLD-STREAM PROBE on d_ws (1 GiB >> 256 MiB L3; every read cold),
// real pipeline (round-5 config) unchanged and feeding d_out.
//   probe_plain     : 2048 blocks, plain dwordx4   -> cold-read ceiling
//   probe_nt        : 2048 blocks, nontemporal     -> does nt matter cold?
//   probe_plain_128 : 128 blocks (128 CUs active)  -> per-CU vs global cap
constexpr int N_ROWS = 65536;
constexpr int D      = 1024;
constexpr int CH     = 128;
constexpr int NCHUNK = 2048;

typedef float f32x4 __attribute__((ext_vector_type(4)));

// ---------------------------------------------------------------------------
// Real K1: nt + moving-window + 8-deep unroll (round-5, known 62 us cold).
// ---------------------------------------------------------------------------
__global__ __launch_bounds__(256, 4) void colsum_partial_kernel(
    const float* __restrict__ x, float* __restrict__ partial, int nchunk) {
    const int tid  = threadIdx.x;
    const int b    = blockIdx.x;
    const int iters = N_ROWS / nchunk;
    const size_t rs   = D / 4;
    const size_t step = (size_t)nchunk * rs;
    const f32x4* __restrict__ xr =
        reinterpret_cast<const f32x4*>(x) + (size_t)b * rs + tid;

    f32x4 a0 = 0.f, a1 = 0.f, a2 = 0.f, a3 = 0.f;
    f32x4 a4 = 0.f, a5 = 0.f, a6 = 0.f, a7 = 0.f;
    for (int j = 0; j < iters; j += 8) {
        const f32x4* p = xr + (size_t)j * step;
        f32x4 v0 = __builtin_nontemporal_load(p + 0 * step);
        f32x4 v1 = __builtin_nontemporal_load(p + 1 * step);
        f32x4 v2 = __builtin_nontemporal_load(p + 2 * step);
        f32x4 v3 = __builtin_nontemporal_load(p + 3 * step);
        f32x4 v4 = __builtin_nontemporal_load(p + 4 * step);
        f32x4 v5 = __builtin_nontemporal_load(p + 5 * step);
        f32x4 v6 = __builtin_nontemporal_load(p + 6 * step);
        f32x4 v7 = __builtin_nontemporal_load(p + 7 * step);
        a0 += v0; a1 += v1; a2 += v2; a3 += v3;
        a4 += v4; a5 += v5; a6 += v6; a7 += v7;
    }
    f32x4 o = ((a0 + a1) + (a2 + a3)) + ((a4 + a5) + (a6 + a7));
    reinterpret_cast<f32x4*>(partial)[(size_t)b * rs + tid] = o;
}

// ---------------------------------------------------------------------------
// Probes: stream `iters`*32KiB per block from a contiguous slab of src.
// Per iteration: 8 x dwordx4 per thread-quarter-row (32 KiB per block-iter).
// ---------------------------------------------------------------------------
__global__ __launch_bounds__(256, 4) void probe_plain(
    const f32x4* __restrict__ src, f32x4* __restrict__ sink, int iters) {
    const int tid = threadIdx.x;
    const size_t b = blockIdx.x;
    const f32x4* __restrict__ p = src + b * (size_t)iters * 2048 + tid;
    f32x4 a0 = 0.f, a1 = 0.f, a2 = 0.f, a3 = 0.f;
    f32x4 a4 = 0.f, a5 = 0.f, a6 = 0.f, a7 = 0.f;
    for (int i = 0; i < iters; ++i) {
        const f32x4* q = p + (size_t)i * 2048;
        a0 += q[0 * 256]; a1 += q[1 * 256]; a2 += q[2 * 256]; a3 += q[3 * 256];
        a4 += q[4 * 256]; a5 += q[5 * 256]; a6 += q[6 * 256]; a7 += q[7 * 256];
    }
    sink[b] = ((a0 + a1) + (a2 + a3)) + ((a4 + a5) + (a6 + a7));
}

__global__ __launch_bounds__(256, 4) void probe_nt(
    const f32x4* __restrict__ src, f32x4* __restrict__ sink, int iters) {
    const int tid = threadIdx.x;
    const size_t b = blockIdx.x;
    const f32x4* __restrict__ p = src + b * (size_t)iters * 2048 + tid;
    f32x4 a0 = 0.f, a1 = 0.f, a2 = 0.f, a3 = 0.f;
    f32x4 a4 = 0.f, a5 = 0.f, a6 = 0.f, a7 = 0.f;
    for (int i = 0; i < iters; ++i) {
        const f32x4* q = p + (size_t)i * 2048;
        a0 += __builtin_nontemporal_load(q + 0 * 256);
        a1 += __builtin_nontemporal_load(q + 1 * 256);
        a2 += __builtin_nontemporal_load(q + 2 * 256);
        a3 += __builtin_nontemporal_load(q + 3 * 256);
        a4 += __builtin_nontemporal_load(q + 4 * 256);
        a5 += __builtin_nontemporal_load(q + 5 * 256);
        a6 += __builtin_nontemporal_load(q + 6 * 256);
        a7 += __builtin_nontemporal_load(q + 7 * 256);
    }
    sink[b] = ((a0 + a1) + (a2 + a3)) + ((a4 + a5) + (a6 + a7));
}

// Distinct name so rocprof rows are unambiguous vs probe_plain.
__global__ __launch_bounds__(256, 4) void probe_plain_128(
    const f32x4* __restrict__ src, f32x4* __restrict__ sink, int iters) {
    const int tid = threadIdx.x;
    const size_t b = blockIdx.x;
    const f32x4* __restrict__ p = src + b * (size_t)iters * 2048 + tid;
    f32x4 a0 = 0.f, a1 = 0.f, a2 = 0.f, a3 = 0.f;
    f32x4 a4 = 0.f, a5 = 0.f, a6 = 0.f, a7 = 0.f;
    for (int i = 0; i < iters; ++i) {
        const f32x4* q = p + (size_t)i * 2048;
        a0 += q[0 * 256]; a1 += q[1 * 256]; a2 += q[2 * 256]; a3 += q[3 * 256];
        a4 += q[4 * 256]; a5 += q[5 * 256]; a6 += q[6 * 256]; a7 += q[7 * 256];
    }
    sink[b] = ((a0 + a1) + (a2 + a3)) + ((a4 + a5) + (a6 + a7));
}

// ---------------------------------------------------------------------------
// K2: blocks 0..127 reduce partial -> c; blocks 128..255 colsum weight -> t.
// ---------------------------------------------------------------------------
__global__ __launch_bounds__(256) void reduce_ct_kernel(
    const float* __restrict__ partial, int nchunk,
    const float* __restrict__ w,
    float* __restrict__ c, float* __restrict__ t) {
    const int b     = blockIdx.x;
    const int tid   = threadIdx.x;
    const int colin = tid & 7;
    const int grp   = tid >> 3;   // 0..31
    __shared__ float red[32][8];

    float acc = 0.f;
    int col;
    if (b < 128) {
        col = b * 8 + colin;
        const int cpg = nchunk >> 5;
        const float* __restrict__ p = partial + (size_t)(grp * cpg) * D + col;
        #pragma unroll 8
        for (int ch = 0; ch < cpg; ++ch) acc += p[(size_t)ch * D];
    } else {
        col = (b - 128) * 8 + colin;
        const float* __restrict__ p = w + (size_t)(grp * (CH / 32)) * D + col;
        #pragma unroll
        for (int r = 0; r < CH / 32; ++r) acc += p[(size_t)r * D];
    }
    red[grp][colin] = acc;
    __syncthreads();
    for (int s = 16; s > 0; s >>= 1) {
        if (grp < s) red[grp][colin] += red[grp + s][colin];
        __syncthreads();
    }
    if (grp == 0) {
        if (b < 128) c[col] = red[0][colin];
        else         t[col] = red[0][colin];
    }
}

// ---------------------------------------------------------------------------
// K3: one block per output row i; shfl-butterfly reductions.
// ---------------------------------------------------------------------------
__global__ __launch_bounds__(256) void out_kernel(
    const float* __restrict__ w, const float* __restrict__ c,
    const float* __restrict__ t, float* __restrict__ out) {
    const int i    = blockIdx.x;
    const int tid  = threadIdx.x;
    const int wid  = tid >> 6;
    const int lane = tid & 63;
    __shared__ float red[8];

    float4 wv = reinterpret_cast<const float4*>(w + (size_t)i * D)[tid];
    float sv = (wv.x + wv.y) + (wv.z + wv.w);
    #pragma unroll
    for (int m = 32; m > 0; m >>= 1) sv += __shfl_xor(sv, m, 64);
    if (lane == 0) red[wid] = sv;
    __syncthreads();
    const float s_i = (red[0] + red[1]) + (red[2] + red[3]);

    float4 cv = reinterpret_cast<const float4*>(c)[tid];
    float ev = (expf(s_i * cv.x) + expf(s_i * cv.y)) +
               (expf(s_i * cv.z) + expf(s_i * cv.w));
    #pragma unroll
    for (int m = 32; m > 0; m >>= 1) ev += __shfl_xor(ev, m, 64);
    if (lane == 0) red[4 + wid] = ev;
    __syncthreads();
    const float inv_det = 1.0f / ((red[4] + red[5]) + (red[6] + red[7]));

    float4 tv = reinterpret_cast<const float4*>(t)[tid];
    float4 o;
    o.x = expf(s_i * tv.x) * inv_det;
    o.y = expf(s_i * tv.y) * inv_det;
    o.z = expf(s_i * tv.z) * inv_det;
    o.w = expf(s_i * tv.w) * inv_det;
    reinterpret_cast<float4*>(out + (size_t)i * D)[tid] = o;
}

// ---------------------------------------------------------------------------
// launch: real pipeline first (d_out correctness), then probes on ws poison.
// ws layout: [0,4K) c | [4K,8K) t | [8K, 8K+8M) partial | [12M,13M) sinks |
//            [16M, 16M+probe_bytes) probe stream (read-only 0xAA poison).
// ---------------------------------------------------------------------------
extern "C" void kernel_launch(void* const* d_in, const int* in_sizes, int n_in,
                              void* d_out, int out_size, void* d_ws, size_t ws_size,
                              hipStream_t stream) {
    const float* x = (const float*)d_in[0];
    const float* w = (const float*)d_in[1];
    float* out = (float*)d_out;

    char* ws = (char*)d_ws;
    float* c       = (float*)(ws);
    float* t       = (float*)(ws + 4096);
    float* partial = (float*)(ws + 8192);
    f32x4* sink1   = (f32x4*)(ws + (12u << 20));
    f32x4* sink2   = (f32x4*)(ws + (12u << 20) + 65536);
    f32x4* sink3   = (f32x4*)(ws + (12u << 20) + 131072);
    const f32x4* probe_src = (const f32x4*)(ws + (16u << 20));

    int nchunk = NCHUNK;
    while (nchunk > 32 && (size_t)nchunk * D * sizeof(float) + 8192 > ws_size)
        nchunk >>= 1;

    // Real pipeline (unchanged round-5 config).
    colsum_partial_kernel<<<nchunk, 256, 0, stream>>>(x, partial, nchunk);
    reduce_ct_kernel<<<256, 256, 0, stream>>>(partial, nchunk, w, c, t);
    out_kernel<<<CH, 256, 0, stream>>>(w, c, t, out);

    // Probes: only if ws has room (needs 16 MiB + >=64 MiB).
    const size_t PROBE_OFF = (size_t)16 << 20;
    const size_t UNIT = (size_t)2048 * 256 * 16 * 8;  // 64 MiB granularity
    size_t avail = (ws_size > PROBE_OFF) ? (ws_size - PROBE_OFF) : 0;
    size_t probe_bytes = (avail / UNIT) * UNIT;
    if (probe_bytes) {
        int iters1 = (int)(probe_bytes >> 26);  // 2048-block probes
        int iters2 = (int)(probe_bytes >> 22);  // 128-block probe
        probe_plain<<<2048, 256, 0, stream>>>(probe_src, sink1, iters1);
        probe_nt<<<2048, 256, 0, stream>>>(probe_src, sink2, iters1);
        probe_plain_128<<<128, 256, 0, stream>>>(probe_src, sink3, iters2);
    }
}

// Round 8
// 57.363 us; speedup vs baseline: 11.6577x; 11.6577x over previous
//
#include <hip/hip_runtime.h>

// Reference: x[65536][1024] f32, weight[128][1024] f32 -> out[128][1024] f32.
// out[i,j] = exp(s_i*t_j)/det_i; s=rowsum(w), t=colsum(w), c=colsum(x),
// det_i = sum_k exp(s_i*c_k).  Mandatory traffic: 256 MiB cold read of x.
//
// Round-7 probe finding: plain loads + contiguous slab + 8 loads in flight
// per wave = ~6.5 TB/s (probe_plain). 4-deep ILP or strided windows = 4.4.
// K1 below is probe_plain's exact structure adapted to colsum.
constexpr int N_ROWS = 65536;
constexpr int D      = 1024;
constexpr int CH     = 128;
constexpr int NCHUNK = 2048;

typedef float f32x4 __attribute__((ext_vector_type(4)));

// ---------------------------------------------------------------------------
// K1: block b owns rows [b*rpb, (b+1)*rpb) (contiguous 128 KiB slab at
// nchunk=2048). Per outer iter: 8 rows of 4 KiB in flight (8 x dwordx4 per
// thread, 4 KiB apart). Thread tid owns columns 4*tid..4*tid+3.
// VGPR ~32 -> 32 waves/CU possible; plain (cached) loads.
// ---------------------------------------------------------------------------
__global__ __launch_bounds__(256, 4) void colsum_partial_kernel(
    const float* __restrict__ x, float* __restrict__ partial, int nchunk) {
    const int tid   = threadIdx.x;
    const size_t b  = blockIdx.x;
    const int rpb   = N_ROWS / nchunk;       // rows per block (32)
    const f32x4* __restrict__ p =
        reinterpret_cast<const f32x4*>(x) + b * (size_t)rpb * 256 + tid;

    f32x4 a0 = 0.f, a1 = 0.f, a2 = 0.f, a3 = 0.f;
    f32x4 a4 = 0.f, a5 = 0.f, a6 = 0.f, a7 = 0.f;
    for (int i = 0; i < rpb / 8; ++i) {
        const f32x4* q = p + (size_t)i * 8 * 256;
        a0 += q[0 * 256]; a1 += q[1 * 256]; a2 += q[2 * 256]; a3 += q[3 * 256];
        a4 += q[4 * 256]; a5 += q[5 * 256]; a6 += q[6 * 256]; a7 += q[7 * 256];
    }
    f32x4 o = ((a0 + a1) + (a2 + a3)) + ((a4 + a5) + (a6 + a7));
    reinterpret_cast<f32x4*>(partial)[b * 256 + tid] = o;
}

// ---------------------------------------------------------------------------
// K2: blocks 0..127 reduce partial[nchunk][1024] -> c[1024] (8 cols/block,
//     32 chunk-groups); blocks 128..255: column-sum weight -> t[1024].
// Fixed order -> deterministic.
// ---------------------------------------------------------------------------
__global__ __launch_bounds__(256) void reduce_ct_kernel(
    const float* __restrict__ partial, int nchunk,
    const float* __restrict__ w,
    float* __restrict__ c, float* __restrict__ t) {
    const int b     = blockIdx.x;
    const int tid   = threadIdx.x;
    const int colin = tid & 7;
    const int grp   = tid >> 3;   // 0..31
    __shared__ float red[32][8];

    float acc = 0.f;
    int col;
    if (b < 128) {
        col = b * 8 + colin;
        const int cpg = nchunk >> 5;
        const float* __restrict__ p = partial + (size_t)(grp * cpg) * D + col;
        #pragma unroll 8
        for (int ch = 0; ch < cpg; ++ch) acc += p[(size_t)ch * D];
    } else {
        col = (b - 128) * 8 + colin;
        const float* __restrict__ p = w + (size_t)(grp * (CH / 32)) * D + col;
        #pragma unroll
        for (int r = 0; r < CH / 32; ++r) acc += p[(size_t)r * D];
    }
    red[grp][colin] = acc;
    __syncthreads();
    for (int s = 16; s > 0; s >>= 1) {
        if (grp < s) red[grp][colin] += red[grp + s][colin];
        __syncthreads();
    }
    if (grp == 0) {
        if (b < 128) c[col] = red[0][colin];
        else         t[col] = red[0][colin];
    }
}

// ---------------------------------------------------------------------------
// K3: one block per output row i; shfl-butterfly reductions.
// ---------------------------------------------------------------------------
__global__ __launch_bounds__(256) void out_kernel(
    const float* __restrict__ w, const float* __restrict__ c,
    const float* __restrict__ t, float* __restrict__ out) {
    const int i    = blockIdx.x;
    const int tid  = threadIdx.x;
    const int wid  = tid >> 6;
    const int lane = tid & 63;
    __shared__ float red[8];

    float4 wv = reinterpret_cast<const float4*>(w + (size_t)i * D)[tid];
    float sv = (wv.x + wv.y) + (wv.z + wv.w);
    #pragma unroll
    for (int m = 32; m > 0; m >>= 1) sv += __shfl_xor(sv, m, 64);
    if (lane == 0) red[wid] = sv;
    __syncthreads();
    const float s_i = (red[0] + red[1]) + (red[2] + red[3]);

    float4 cv = reinterpret_cast<const float4*>(c)[tid];
    float ev = (expf(s_i * cv.x) + expf(s_i * cv.y)) +
               (expf(s_i * cv.z) + expf(s_i * cv.w));
    #pragma unroll
    for (int m = 32; m > 0; m >>= 1) ev += __shfl_xor(ev, m, 64);
    if (lane == 0) red[4 + wid] = ev;
    __syncthreads();
    const float inv_det = 1.0f / ((red[4] + red[5]) + (red[6] + red[7]));

    float4 tv = reinterpret_cast<const float4*>(t)[tid];
    float4 o;
    o.x = expf(s_i * tv.x) * inv_det;
    o.y = expf(s_i * tv.y) * inv_det;
    o.z = expf(s_i * tv.z) * inv_det;
    o.w = expf(s_i * tv.w) * inv_det;
    reinterpret_cast<float4*>(out + (size_t)i * D)[tid] = o;
}

// ---------------------------------------------------------------------------
// launch
// ---------------------------------------------------------------------------
extern "C" void kernel_launch(void* const* d_in, const int* in_sizes, int n_in,
                              void* d_out, int out_size, void* d_ws, size_t ws_size,
                              hipStream_t stream) {
    const float* x = (const float*)d_in[0];
    const float* w = (const float*)d_in[1];
    float* out = (float*)d_out;

    char* ws = (char*)d_ws;
    float* c       = (float*)(ws);
    float* t       = (float*)(ws + 4096);
    float* partial = (float*)(ws + 8192);

    int nchunk = NCHUNK;
    while (nchunk > 32 && (size_t)nchunk * D * sizeof(float) + 8192 > ws_size)
        nchunk >>= 1;

    colsum_partial_kernel<<<nchunk, 256, 0, stream>>>(x, partial, nchunk);
    reduce_ct_kernel<<<256, 256, 0, stream>>>(partial, nchunk, w, c, t);
    out_kernel<<<CH, 256, 0, stream>>>(w, c, t, out);
}

// Round 9
// 54.175 us; speedup vs baseline: 12.3438x; 1.0589x over previous
//
#include <hip/hip_runtime.h>

// Reference: x[65536][1024] f32, weight[128][1024] f32 -> out[128][1024] f32.
// out[i,j] = exp(s_i*t_j)/det_i; s=rowsum(w), t=colsum(w), c=colsum(x),
// det_i = sum_k exp(s_i*c_k).  Mandatory traffic: 256 MiB cold read of x.
//
// r7 probe: plain loads + contiguous slab + 8 loads in flight = ~6.5 TB/s.
// r8: that structure at 2048 blocks (4 outer iters) = ~5.8 TB/s. This round:
// nchunk=1024 (8 outer iters, 256 KiB slab/block) to amortize ramp/drain,
// matching the probe's longer per-block stream.
constexpr int N_ROWS = 65536;
constexpr int D      = 1024;
constexpr int CH     = 128;
constexpr int NCHUNK = 1024;

typedef float f32x4 __attribute__((ext_vector_type(4)));

// ---------------------------------------------------------------------------
// K1: block b owns rows [b*rpb, (b+1)*rpb) — contiguous 256 KiB slab at
// nchunk=1024. Per outer iter: 8 rows (32 KiB/block) in flight, 8 independent
// accumulators. Thread tid owns columns 4*tid..4*tid+3. VGPR ~32.
// ---------------------------------------------------------------------------
__global__ __launch_bounds__(256, 4) void colsum_partial_kernel(
    const float* __restrict__ x, float* __restrict__ partial, int nchunk) {
    const int tid   = threadIdx.x;
    const size_t b  = blockIdx.x;
    const int rpb   = N_ROWS / nchunk;       // rows per block (64)
    const f32x4* __restrict__ p =
        reinterpret_cast<const f32x4*>(x) + b * (size_t)rpb * 256 + tid;

    f32x4 a0 = 0.f, a1 = 0.f, a2 = 0.f, a3 = 0.f;
    f32x4 a4 = 0.f, a5 = 0.f, a6 = 0.f, a7 = 0.f;
    for (int i = 0; i < rpb / 8; ++i) {
        const f32x4* q = p + (size_t)i * 8 * 256;
        a0 += q[0 * 256]; a1 += q[1 * 256]; a2 += q[2 * 256]; a3 += q[3 * 256];
        a4 += q[4 * 256]; a5 += q[5 * 256]; a6 += q[6 * 256]; a7 += q[7 * 256];
    }
    f32x4 o = ((a0 + a1) + (a2 + a3)) + ((a4 + a5) + (a6 + a7));
    reinterpret_cast<f32x4*>(partial)[b * 256 + tid] = o;
}

// ---------------------------------------------------------------------------
// K2: blocks 0..127 reduce partial[nchunk][1024] -> c[1024] (8 cols/block,
//     32 chunk-groups); blocks 128..255: column-sum weight -> t[1024].
// Fixed order -> deterministic.
// ---------------------------------------------------------------------------
__global__ __launch_bounds__(256) void reduce_ct_kernel(
    const float* __restrict__ partial, int nchunk,
    const float* __restrict__ w,
    float* __restrict__ c, float* __restrict__ t) {
    const int b     = blockIdx.x;
    const int tid   = threadIdx.x;
    const int colin = tid & 7;
    const int grp   = tid >> 3;   // 0..31
    __shared__ float red[32][8];

    float acc = 0.f;
    int col;
    if (b < 128) {
        col = b * 8 + colin;
        const int cpg = nchunk >> 5;   // 32 @ nchunk=1024
        const float* __restrict__ p = partial + (size_t)(grp * cpg) * D + col;
        #pragma unroll 8
        for (int ch = 0; ch < cpg; ++ch) acc += p[(size_t)ch * D];
    } else {
        col = (b - 128) * 8 + colin;
        const float* __restrict__ p = w + (size_t)(grp * (CH / 32)) * D + col;
        #pragma unroll
        for (int r = 0; r < CH / 32; ++r) acc += p[(size_t)r * D];
    }
    red[grp][colin] = acc;
    __syncthreads();
    for (int s = 16; s > 0; s >>= 1) {
        if (grp < s) red[grp][colin] += red[grp + s][colin];
        __syncthreads();
    }
    if (grp == 0) {
        if (b < 128) c[col] = red[0][colin];
        else         t[col] = red[0][colin];
    }
}

// ---------------------------------------------------------------------------
// K3: one block per output row i; shfl-butterfly reductions.
// ---------------------------------------------------------------------------
__global__ __launch_bounds__(256) void out_kernel(
    const float* __restrict__ w, const float* __restrict__ c,
    const float* __restrict__ t, float* __restrict__ out) {
    const int i    = blockIdx.x;
    const int tid  = threadIdx.x;
    const int wid  = tid >> 6;
    const int lane = tid & 63;
    __shared__ float red[8];

    float4 wv = reinterpret_cast<const float4*>(w + (size_t)i * D)[tid];
    float sv = (wv.x + wv.y) + (wv.z + wv.w);
    #pragma unroll
    for (int m = 32; m > 0; m >>= 1) sv += __shfl_xor(sv, m, 64);
    if (lane == 0) red[wid] = sv;
    __syncthreads();
    const float s_i = (red[0] + red[1]) + (red[2] + red[3]);

    float4 cv = reinterpret_cast<const float4*>(c)[tid];
    float ev = (expf(s_i * cv.x) + expf(s_i * cv.y)) +
               (expf(s_i * cv.z) + expf(s_i * cv.w));
    #pragma unroll
    for (int m = 32; m > 0; m >>= 1) ev += __shfl_xor(ev, m, 64);
    if (lane == 0) red[4 + wid] = ev;
    __syncthreads();
    const float inv_det = 1.0f / ((red[4] + red[5]) + (red[6] + red[7]));

    float4 tv = reinterpret_cast<const float4*>(t)[tid];
    float4 o;
    o.x = expf(s_i * tv.x) * inv_det;
    o.y = expf(s_i * tv.y) * inv_det;
    o.z = expf(s_i * tv.z) * inv_det;
    o.w = expf(s_i * tv.w) * inv_det;
    reinterpret_cast<float4*>(out + (size_t)i * D)[tid] = o;
}

// ---------------------------------------------------------------------------
// launch
// ---------------------------------------------------------------------------
extern "C" void kernel_launch(void* const* d_in, const int* in_sizes, int n_in,
                              void* d_out, int out_size, void* d_ws, size_t ws_size,
                              hipStream_t stream) {
    const float* x = (const float*)d_in[0];
    const float* w = (const float*)d_in[1];
    float* out = (float*)d_out;

    char* ws = (char*)d_ws;
    float* c       = (float*)(ws);
    float* t       = (float*)(ws + 4096);
    float* partial = (float*)(ws + 8192);

    int nchunk = NCHUNK;
    while (nchunk > 32 && (size_t)nchunk * D * sizeof(float) + 8192 > ws_size)
        nchunk >>= 1;

    colsum_partial_kernel<<<nchunk, 256, 0, stream>>>(x, partial, nchunk);
    reduce_ct_kernel<<<256, 256, 0, stream>>>(partial, nchunk, w, c, t);
    out_kernel<<<CH, 256, 0, stream>>>(w, c, t, out);
}

// Round 10
// 50.501 us; speedup vs baseline: 13.2419x; 1.0728x over previous
//
#include <hip/hip_runtime.h>

// Reference: x[65536][1024] f32, weight[128][1024] f32 -> out[128][1024] f32.
// out[i,j] = exp(s_i*t_j)/det_i; s=rowsum(w), t=colsum(w), c=colsum(x),
// det_i = sum_k exp(s_i*c_k).  Mandatory traffic: 256 MiB cold read of x.
//
// Ladder: r7 probe showed plain loads + contiguous slab + 8 loads in flight
// = ~6.5 TB/s; r8 (4 outer iters/block) 57.4 us; r9 (8 iters) 54.2 us.
// r10: 16 outer iters (nchunk=512, 512 KiB slab/block, 8 waves/CU).
constexpr int N_ROWS = 65536;
constexpr int D      = 1024;
constexpr int CH     = 128;
constexpr int NCHUNK = 512;

typedef float f32x4 __attribute__((ext_vector_type(4)));

// ---------------------------------------------------------------------------
// K1: block b owns rows [b*rpb, (b+1)*rpb) — contiguous 512 KiB slab at
// nchunk=512 (rpb=128). Per outer iter: 8 rows (32 KiB/block) in flight,
// 8 independent accumulators. Thread tid owns columns 4*tid..4*tid+3.
// ---------------------------------------------------------------------------
__global__ __launch_bounds__(256, 4) void colsum_partial_kernel(
    const float* __restrict__ x, float* __restrict__ partial, int nchunk) {
    const int tid   = threadIdx.x;
    const size_t b  = blockIdx.x;
    const int rpb   = N_ROWS / nchunk;       // rows per block (128)
    const f32x4* __restrict__ p =
        reinterpret_cast<const f32x4*>(x) + b * (size_t)rpb * 256 + tid;

    f32x4 a0 = 0.f, a1 = 0.f, a2 = 0.f, a3 = 0.f;
    f32x4 a4 = 0.f, a5 = 0.f, a6 = 0.f, a7 = 0.f;
    for (int i = 0; i < rpb / 8; ++i) {
        const f32x4* q = p + (size_t)i * 8 * 256;
        a0 += q[0 * 256]; a1 += q[1 * 256]; a2 += q[2 * 256]; a3 += q[3 * 256];
        a4 += q[4 * 256]; a5 += q[5 * 256]; a6 += q[6 * 256]; a7 += q[7 * 256];
    }
    f32x4 o = ((a0 + a1) + (a2 + a3)) + ((a4 + a5) + (a6 + a7));
    reinterpret_cast<f32x4*>(partial)[b * 256 + tid] = o;
}

// ---------------------------------------------------------------------------
// K2: blocks 0..127 reduce partial[nchunk][1024] -> c[1024] (8 cols/block,
//     32 chunk-groups x 16 chunks); blocks 128..255: colsum weight -> t.
// Fixed order -> deterministic.
// ---------------------------------------------------------------------------
__global__ __launch_bounds__(256) void reduce_ct_kernel(
    const float* __restrict__ partial, int nchunk,
    const float* __restrict__ w,
    float* __restrict__ c, float* __restrict__ t) {
    const int b     = blockIdx.x;
    const int tid   = threadIdx.x;
    const int colin = tid & 7;
    const int grp   = tid >> 3;   // 0..31
    __shared__ float red[32][8];

    float acc = 0.f;
    int col;
    if (b < 128) {
        col = b * 8 + colin;
        const int cpg = nchunk >> 5;   // 16 @ nchunk=512
        const float* __restrict__ p = partial + (size_t)(grp * cpg) * D + col;
        #pragma unroll 8
        for (int ch = 0; ch < cpg; ++ch) acc += p[(size_t)ch * D];
    } else {
        col = (b - 128) * 8 + colin;
        const float* __restrict__ p = w + (size_t)(grp * (CH / 32)) * D + col;
        #pragma unroll
        for (int r = 0; r < CH / 32; ++r) acc += p[(size_t)r * D];
    }
    red[grp][colin] = acc;
    __syncthreads();
    for (int s = 16; s > 0; s >>= 1) {
        if (grp < s) red[grp][colin] += red[grp + s][colin];
        __syncthreads();
    }
    if (grp == 0) {
        if (b < 128) c[col] = red[0][colin];
        else         t[col] = red[0][colin];
    }
}

// ---------------------------------------------------------------------------
// K3: one block per output row i; shfl-butterfly reductions.
// ---------------------------------------------------------------------------
__global__ __launch_bounds__(256) void out_kernel(
    const float* __restrict__ w, const float* __restrict__ c,
    const float* __restrict__ t, float* __restrict__ out) {
    const int i    = blockIdx.x;
    const int tid  = threadIdx.x;
    const int wid  = tid >> 6;
    const int lane = tid & 63;
    __shared__ float red[8];

    float4 wv = reinterpret_cast<const float4*>(w + (size_t)i * D)[tid];
    float sv = (wv.x + wv.y) + (wv.z + wv.w);
    #pragma unroll
    for (int m = 32; m > 0; m >>= 1) sv += __shfl_xor(sv, m, 64);
    if (lane == 0) red[wid] = sv;
    __syncthreads();
    const float s_i = (red[0] + red[1]) + (red[2] + red[3]);

    float4 cv = reinterpret_cast<const float4*>(c)[tid];
    float ev = (expf(s_i * cv.x) + expf(s_i * cv.y)) +
               (expf(s_i * cv.z) + expf(s_i * cv.w));
    #pragma unroll
    for (int m = 32; m > 0; m >>= 1) ev += __shfl_xor(ev, m, 64);
    if (lane == 0) red[4 + wid] = ev;
    __syncthreads();
    const float inv_det = 1.0f / ((red[4] + red[5]) + (red[6] + red[7]));

    float4 tv = reinterpret_cast<const float4*>(t)[tid];
    float4 o;
    o.x = expf(s_i * tv.x) * inv_det;
    o.y = expf(s_i * tv.y) * inv_det;
    o.z = expf(s_i * tv.z) * inv_det;
    o.w = expf(s_i * tv.w) * inv_det;
    reinterpret_cast<float4*>(out + (size_t)i * D)[tid] = o;
}

// ---------------------------------------------------------------------------
// launch
// ---------------------------------------------------------------------------
extern "C" void kernel_launch(void* const* d_in, const int* in_sizes, int n_in,
                              void* d_out, int out_size, void* d_ws, size_t ws_size,
                              hipStream_t stream) {
    const float* x = (const float*)d_in[0];
    const float* w = (const float*)d_in[1];
    float* out = (float*)d_out;

    char* ws = (char*)d_ws;
    float* c       = (float*)(ws);
    float* t       = (float*)(ws + 4096);
    float* partial = (float*)(ws + 8192);

    int nchunk = NCHUNK;
    while (nchunk > 32 && (size_t)nchunk * D * sizeof(float) + 8192 > ws_size)
        nchunk >>= 1;

    colsum_partial_kernel<<<nchunk, 256, 0, stream>>>(x, partial, nchunk);
    reduce_ct_kernel<<<256, 256, 0, stream>>>(partial, nchunk, w, c, t);
    out_kernel<<<CH, 256, 0, stream>>>(w, c, t, out);
}